// Round 10
// baseline (3351.003 us; speedup 1.0000x reference)
//
#include <hip/hip_runtime.h>
#include <stdint.h>

#define Tt 1024
#define Bt 128
#define Vt 256
#define TS 32768  // shorts per t-slice

typedef __attribute__((ext_vector_type(8))) short bf16x8;
typedef __attribute__((ext_vector_type(4))) float f32x4;
typedef __attribute__((ext_vector_type(4))) int i32x4;

#define MFMA(a, b, c) __builtin_amdgcn_mfma_f32_16x16x32_bf16(a, b, c, 0, 0, 0)
#define SENT 0x7FFF  // bf16 NaN: unreachable from f2bf(finite h in (-1,1))

// ---- geometry ---------------------------------------------------------------
// Per layer 64 WGs = 8 bgrp (16 batch rows) x 8 cgrp (32 h-cols). Waves are
// COL-SPLIT (wave wv owns 8 h-cols, computes ALL 4 gates for them): cell is
// in-register via shfl_xor(8) -- NO per-step __syncthreads (R4-proven),
// combined with R9's low-fan-in contiguous tile exchange (R9-proven).
// h slice layout: [bgrp(8)][cgrp(8)][sub(4)=wave][row(16)][col(8)] shorts.
//   producer: wave wv stores its 512B slice with ONE 16-lane x 16B instr.
//   consumer frag (kb,q,ln) = 16B at kb*512 + q*128 + ln*8 shorts -- exactly
//   one producer lane-store (atomic); fan-in still 8 tiles / 8 poll loads.

__device__ __forceinline__ unsigned short f2bf(float f) {
    unsigned u = __builtin_bit_cast(unsigned, f);
    u += 0x7fffu + ((u >> 16) & 1u);
    return (unsigned short)(u >> 16);
}
__device__ __forceinline__ float sigm(float x) {
    return __builtin_amdgcn_rcpf(1.f + __expf(-x));
}
__device__ __forceinline__ float tanh_f(float x) {
    float e = __expf(-2.f * fabsf(x));
    float t = (1.f - e) * __builtin_amdgcn_rcpf(1.f + e);
    return copysignf(t, x);
}

// agent-coherent 16B load (sc0 sc1: MALL path). global offset: is 13-bit
// signed (<=4095) -> two bases, offsets 0..3072.
template <int OFF>
__device__ __forceinline__ bf16x8 ldcc(const unsigned short* p) {
    bf16x8 d;
    asm volatile("global_load_dwordx4 %0, %1, off offset:%c2 sc0 sc1"
                 : "=v"(d) : "v"(p), "i"(OFF));
    return d;
}
#define LD8T(d, P)                                        \
    do {                                                  \
        const unsigned short* _p2 = (P) + 2048;           \
        d[0] = ldcc<0>(P);      d[1] = ldcc<1024>(P);     \
        d[2] = ldcc<2048>(P);   d[3] = ldcc<3072>(P);     \
        d[4] = ldcc<0>(_p2);    d[5] = ldcc<1024>(_p2);   \
        d[6] = ldcc<2048>(_p2); d[7] = ldcc<3072>(_p2);   \
    } while (0)

__device__ __forceinline__ void vm_drain() {
    asm volatile("s_waitcnt vmcnt(0)" ::: "memory");
    __builtin_amdgcn_sched_barrier(0);  // rule #18
}
__device__ __forceinline__ int fdirty(bf16x8 f) {
    i32x4 d = __builtin_bit_cast(i32x4, f);
    return ((d.x & 0xFFFF) == SENT) | ((d.z & 0xFFFF) == SENT);
}

// ---------------- x [B,T,V] fp32 -> xT [T,B,V] bf16 ----------------
__global__ __launch_bounds__(256) void cvt_kernel(const float* __restrict__ x,
                                                  unsigned short* __restrict__ xT) {
    unsigned g = blockIdx.x * 256u + threadIdx.x;
    unsigned base = g * 8u;
    unsigned r = base >> 8;  // r = t*128 + b
    unsigned v = base & 255u;
    unsigned t = r >> 7, b = r & 127u;
    const float4* src = (const float4*)(x + ((size_t)b * Tt + t) * Vt + v);
    float4 f0 = src[0], f1 = src[1];
    union { unsigned short s[8]; int4 q; } o;
    o.s[0] = f2bf(f0.x); o.s[1] = f2bf(f0.y); o.s[2] = f2bf(f0.z); o.s[3] = f2bf(f0.w);
    o.s[4] = f2bf(f1.x); o.s[5] = f2bf(f1.y); o.s[6] = f2bf(f1.z); o.s[7] = f2bf(f1.w);
    *(int4*)(xT + (size_t)r * Vt + v) = o.q;
}

// ---------------- sentinel pre-fill ----------------
__global__ __launch_bounds__(256) void fill_kernel(unsigned short* __restrict__ h) {
    size_t i = ((size_t)blockIdx.x * 256u + threadIdx.x) * 16u;  // shorts
    i32x4 s = (i32x4){0x7FFF7FFF, 0x7FFF7FFF, 0x7FFF7FFF, 0x7FFF7FFF};
    *(i32x4*)(h + i) = s;
    *(i32x4*)(h + i + 8) = s;
}

// ---------------- persistent dataflow recurrence: 128 WGs ----------------
__global__ __launch_bounds__(256) void rec_kernel(
    const float* __restrict__ Wih1, const float* __restrict__ Whh1,
    const float* __restrict__ bih1, const float* __restrict__ bhh1,
    const float* __restrict__ Wih2, const float* __restrict__ Whh2,
    const float* __restrict__ bih2, const float* __restrict__ bhh2,
    const unsigned short* __restrict__ xT,
    unsigned short* h1s, unsigned short* h2s) {
    const int bid = blockIdx.x;
    const int layer = bid >> 6;
    const int cgrp = (bid >> 3) & 7;  // 32 h-cols [32cgrp, 32cgrp+32)
    const int bgrp = bid & 7;         // 16 batch rows [16bgrp, 16bgrp+16)

    const float* Win = layer ? Wih2 : Wih1;
    const float* Whh = layer ? Whh2 : Whh1;
    const float* bi = layer ? bih2 : bih1;
    const float* bh = layer ? bhh2 : bhh1;

    // per-wave 32 rows: lr -> gate lr>>3, local col lr&7; global gate row =
    // 256*gate + 32*cgrp + 8*wv + local. B-frag nb reads rows nb*16+ln (R4
    // layout: nb=0 -> i|f, nb=1 -> g|o). Pad 264 -> <=2-way b128 conflicts.
    __shared__ unsigned short sW[2][4][32][264];  // 132KB
    __shared__ unsigned short sH[4][16][8];       // per-wave-private transpose

    const int tid = threadIdx.x;
    {   // stage both matrices: thread -> (row tid>>1 of 128, K-half tid&1)
        int row = tid >> 1, seg = (tid & 1) * 128;
        int wvs = row >> 5, lr = row & 31, gate = lr >> 3, loc = lr & 7;
        size_t grow = (size_t)(256 * gate + 32 * cgrp + 8 * wvs + loc) * Vt + seg;
        for (int m = 0; m < 2; ++m) {
            const float* src = (m ? Whh : Win) + grow;
            unsigned short* dst = &sW[m][wvs][lr][seg];
            for (int k = 0; k < 128; k += 4) {
                float4 f = *(const float4*)(src + k);
                dst[k + 0] = f2bf(f.x); dst[k + 1] = f2bf(f.y);
                dst[k + 2] = f2bf(f.z); dst[k + 3] = f2bf(f.w);
            }
        }
    }
    __syncthreads();  // only barrier in the kernel: weights staged

    const int lane = tid & 63;
    const int wv = tid >> 6;   // wave owns h-cols [32cgrp+8wv, +8)
    const int q = lane >> 4;
    const int ln = lane & 15;

    float biasv[2];
#pragma unroll
    for (int nb = 0; nb < 2; ++nb) {
        int gate = nb * 2 + (ln >> 3);
        int grow = 256 * gate + 32 * cgrp + 8 * wv + (ln & 7);
        biasv[nb] = bi[grow] + bh[grow];
    }
    float cst[4] = {0.f, 0.f, 0.f, 0.f};

    // consumer A-frag base: [bgrp][cgrp=kb][sub=q][row=ln][8]
    const size_t hbase = (size_t)bgrp * 4096 + q * 128 + ln * 8;
    const int xoff = (16 * bgrp + ln) * 256 + q * 8;  // xT row-major frag
    unsigned short* ob = layer ? h2s : h1s;
    // producer: wave wv's 512B slice, 16 lanes x 16B (lane = row)
    unsigned short* sptr =
        ob + (size_t)bgrp * 4096 + cgrp * 512 + wv * 128 + lane * 8;

    for (int t = 0; t < Tt; ++t) {
        f32x4 acc[2];
        acc[0] = (f32x4){biasv[0], biasv[0], biasv[0], biasv[0]};
        acc[1] = (f32x4){biasv[1], biasv[1], biasv[1], biasv[1]};
        bf16x8 a1[8], a2[8];

        if (layer == 0) {
            // x loads FIRST (older in vmcnt FIFO -> x-GEMM waits only on them)
            const unsigned short* xp = xT + (size_t)t * TS + xoff;
#pragma unroll
            for (int kb = 0; kb < 8; ++kb) a1[kb] = *(const bf16x8*)(xp + kb * 32);
            const unsigned short* hp = h1s + (size_t)(t - 1) * TS + hbase;
            if (t > 0) LD8T(a2, hp);
            // x-GEMM
#pragma unroll
            for (int kb = 0; kb < 8; ++kb) {
                bf16x8 b0 = *(const bf16x8*)&sW[0][wv][ln][kb * 32 + q * 8];
                bf16x8 b1 = *(const bf16x8*)&sW[0][wv][16 + ln][kb * 32 + q * 8];
                acc[0] = MFMA(a1[kb], b0, acc[0]);
                acc[1] = MFMA(a1[kb], b1, acc[1]);
            }
            if (t > 0) {
                for (;;) {  // sentinel poll: clean => operands already in regs
                    vm_drain();
                    int d = 0;
#pragma unroll
                    for (int kb = 0; kb < 8; ++kb) d |= fdirty(a2[kb]);
                    if (!__any(d)) break;
                    __builtin_amdgcn_s_sleep(1);
                    LD8T(a2, hp);
                }
#pragma unroll
                for (int kb = 0; kb < 8; ++kb) {
                    bf16x8 b0 = *(const bf16x8*)&sW[1][wv][ln][kb * 32 + q * 8];
                    bf16x8 b1 = *(const bf16x8*)&sW[1][wv][16 + ln][kb * 32 + q * 8];
                    acc[0] = MFMA(a2[kb], b0, acc[0]);
                    acc[1] = MFMA(a2[kb], b1, acc[1]);
                }
            }
        } else {
            const unsigned short* hp1 = h1s + (size_t)t * TS + hbase;
            const unsigned short* hp2 = h2s + (size_t)(t - 1) * TS + hbase;
            LD8T(a1, hp1);
            if (t > 0) LD8T(a2, hp2);
            unsigned need = (t > 0) ? 3u : 1u;
            for (;;) {  // combined poll, one drain for both operand sets
                vm_drain();
                unsigned nm = 0;
                if (need & 1) {
                    int d = 0;
#pragma unroll
                    for (int kb = 0; kb < 8; ++kb) d |= fdirty(a1[kb]);
                    if (__any(d)) nm |= 1u;
                }
                if (need & 2) {
                    int d = 0;
#pragma unroll
                    for (int kb = 0; kb < 8; ++kb) d |= fdirty(a2[kb]);
                    if (__any(d)) nm |= 2u;
                }
                if (!nm) break;
                need = nm;
                __builtin_amdgcn_s_sleep(1);
                if (nm & 1) LD8T(a1, hp1);
                if (nm & 2) LD8T(a2, hp2);
            }
#pragma unroll
            for (int kb = 0; kb < 8; ++kb) {
                bf16x8 b0 = *(const bf16x8*)&sW[0][wv][ln][kb * 32 + q * 8];
                bf16x8 b1 = *(const bf16x8*)&sW[0][wv][16 + ln][kb * 32 + q * 8];
                acc[0] = MFMA(a1[kb], b0, acc[0]);
                acc[1] = MFMA(a1[kb], b1, acc[1]);
            }
            if (t > 0) {
#pragma unroll
                for (int kb = 0; kb < 8; ++kb) {
                    bf16x8 b0 = *(const bf16x8*)&sW[1][wv][ln][kb * 32 + q * 8];
                    bf16x8 b1 = *(const bf16x8*)&sW[1][wv][16 + ln][kb * 32 + q * 8];
                    acc[0] = MFMA(a2[kb], b0, acc[0]);
                    acc[1] = MFMA(a2[kb], b1, acc[1]);
                }
            }
        }

        // in-register cell (R4): lane ln holds (i|f) in acc[0], (g|o) in acc[1]
#pragma unroll
        for (int r = 0; r < 4; ++r) {
            float a0 = acc[0][r], a1v = acc[1][r];
            float b0 = __shfl_xor(a0, 8), b1 = __shfl_xor(a1v, 8);
            float iv, fv, gv, ov;
            if (ln < 8) { iv = a0; fv = b0; gv = a1v; ov = b1; }
            else        { iv = b0; fv = a0; gv = b1; ov = a1v; }
            float ii = sigm(iv), ff = sigm(fv), gg = tanh_f(gv), oo = sigm(ov);
            float cc = ff * cst[r] + ii * gg;
            cst[r] = cc;
            float hh = oo * tanh_f(cc);
            if (ln < 8) sH[wv][q * 4 + r][ln] = f2bf(hh);  // batch q*4+r, col ln
        }
        // wave-private transpose: cross-lane within this wave only -> no barrier
        asm volatile("s_waitcnt lgkmcnt(0)" ::: "memory");
        __builtin_amdgcn_sched_barrier(0);
        if (lane < 16) {  // ONE 256-short slice store: lane = row, 16B each
            bf16x8 hv = *(const bf16x8*)&sH[wv][lane][0];
            unsigned short* dst = sptr + (size_t)t * TS;
            asm volatile("global_store_dwordx4 %0, %1, off sc0 sc1" ::"v"(dst),
                         "v"(hv) : "memory");
        }
    }
}

// ---------------- out[b,t,:] = h2s_tiled[t] @ w_n^T + fc_b ----------------
__global__ __launch_bounds__(256) void fc_kernel(const unsigned short* __restrict__ h2s,
                                                 const float* __restrict__ fcw,
                                                 const float* __restrict__ fcb,
                                                 float* __restrict__ out) {
    const int bid = blockIdx.x;
    const int rb = bid >> 2;  // t
    const int c0 = (bid & 3) * 64;
    __shared__ unsigned short sWf[64][264];
    __shared__ float sInv[64];
    const int tid = threadIdx.x;
    if (tid < 64) {
        const float* wr = fcw + (size_t)(c0 + tid) * 256;
        float s = 0.f;
        for (int k = 0; k < 256; k += 4) {
            float4 f = *(const float4*)(wr + k);
            s += f.x * f.x + f.y * f.y + f.z * f.z + f.w * f.w;
        }
        sInv[tid] = rsqrtf(s);
    }
    __syncthreads();
    {
        int lr = tid & 63, seg = tid >> 6;
        float inv = sInv[lr];
        const float* wr = fcw + (size_t)(c0 + lr) * 256 + seg * 64;
        unsigned short* dst = &sWf[lr][seg * 64];
        for (int k = 0; k < 64; k += 4) {
            float4 f = *(const float4*)(wr + k);
            dst[k + 0] = f2bf(f.x * inv); dst[k + 1] = f2bf(f.y * inv);
            dst[k + 2] = f2bf(f.z * inv); dst[k + 3] = f2bf(f.w * inv);
        }
    }
    __syncthreads();
    const int lane = tid & 63, w = tid >> 6, q = lane >> 4, ln = lane & 15;
    f32x4 acc[2][4];
    for (int rk = 0; rk < 2; ++rk)
        for (int nb = 0; nb < 4; ++nb) {
            float bv = fcb[c0 + nb * 16 + ln];
            acc[rk][nb] = (f32x4){bv, bv, bv, bv};
        }
    // h2 layout [bgrp][cgrp][sub][16][8]; wave w covers bgrps {2w, 2w+1};
    // frag(rk, kb) = bgrp 2w+rk, kb*512 + q*128 + ln*8 shorts
    const unsigned short* P0 = h2s + (size_t)rb * TS + (2 * w) * 4096 + q * 128 + ln * 8;
    const unsigned short* P1 = P0 + 4096;
    for (int kb = 0; kb < 8; ++kb) {
        bf16x8 a0 = *(const bf16x8*)(P0 + kb * 512);
        bf16x8 a1 = *(const bf16x8*)(P1 + kb * 512);
        for (int nb = 0; nb < 4; ++nb) {
            bf16x8 b = *(const bf16x8*)&sWf[nb * 16 + ln][kb * 32 + q * 8];
            acc[0][nb] = MFMA(a0, b, acc[0][nb]);
            acc[1][nb] = MFMA(a1, b, acc[1][nb]);
        }
    }
    for (int rk = 0; rk < 2; ++rk)
        for (int nb = 0; nb < 4; ++nb)
            for (int r = 0; r < 4; ++r) {
                int bb = 32 * w + rk * 16 + q * 4 + r;
                int o = c0 + nb * 16 + ln;
                out[((size_t)bb * Tt + rb) * 256 + o] = acc[rk][nb][r];
            }
}

extern "C" void kernel_launch(void* const* d_in, const int* in_sizes, int n_in,
                              void* d_out, int out_size, void* d_ws, size_t ws_size,
                              hipStream_t stream) {
    const float* x    = (const float*)d_in[0];
    const float* Wih1 = (const float*)d_in[1];
    const float* Whh1 = (const float*)d_in[2];
    const float* bih1 = (const float*)d_in[3];
    const float* bhh1 = (const float*)d_in[4];
    const float* Wih2 = (const float*)d_in[5];
    const float* Whh2 = (const float*)d_in[6];
    const float* bih2 = (const float*)d_in[7];
    const float* bhh2 = (const float*)d_in[8];
    const float* fcw  = (const float*)d_in[9];
    const float* fcb  = (const float*)d_in[10];

    char* ws = (char*)d_ws;
    unsigned short* xT  = (unsigned short*)ws;         // 64MB
    unsigned short* h1s = xT + (size_t)Tt * TS;        // 64MB
    unsigned short* h2s = h1s + (size_t)Tt * TS;       // 64MB

    fill_kernel<<<16384, 256, 0, stream>>>(h1s);  // h1s+h2s contiguous 128MB
    cvt_kernel<<<16384, 256, 0, stream>>>(x, xT);
    rec_kernel<<<128, 256, 0, stream>>>(Wih1, Whh1, bih1, bhh1,
                                        Wih2, Whh2, bih2, bhh2,
                                        xT, h1s, h2s);
    fc_kernel<<<4096, 256, 0, stream>>>(h2s, fcw, fcb, (float*)d_out);
}

// Round 11
// 2865.731 us; speedup vs baseline: 1.1693x; 1.1693x over previous
//
#include <hip/hip_runtime.h>
#include <stdint.h>

#define Tt 1024
#define Bt 128
#define Vt 256
#define TS 32768  // shorts per t-slice

typedef __attribute__((ext_vector_type(8))) short bf16x8;
typedef __attribute__((ext_vector_type(4))) float f32x4;
typedef __attribute__((ext_vector_type(4))) int i32x4;

#define MFMA(a, b, c) __builtin_amdgcn_mfma_f32_16x16x32_bf16(a, b, c, 0, 0, 0)
#define SENT 0x7FFF  // bf16 NaN: unreachable from f2bf(finite h in (-1,1))

// ---- geometry ---------------------------------------------------------------
// Per layer 64 WGs = 8 bgrp (16 batch rows) x 8 cgrp (32 h-cols = 128 gate
// rows). NEW: waves split 2x2 over (col-half cs, K-half ks):
//   wave wv = cs*2 + ks; each wave: N = 4 gates x 16 cols, K = 128.
//   => each wave polls only 4 h-fragments per operand (was 8) -- the poll
//   width is the measured dominant lever (R4:16->R9:8 halved the period).
// ks-partials summed via LDS (sP) with the same 2-barrier budget as R9.
// Cell: D-col = lane = h-col, so acc[0..3][r] = i,f,g,o lane-locally (no shfl).
// Producer store: R9's proven single 1KB tile store by one wave.
// h slice layout: [bgrp(8)][cgrp(8)][row(16)][col(32)] shorts; consumer frag
// (tile j, row ln, cols q*8..+8) = exactly one producer 16B lane-store.

__device__ __forceinline__ unsigned short f2bf(float f) {
    unsigned u = __builtin_bit_cast(unsigned, f);
    u += 0x7fffu + ((u >> 16) & 1u);
    return (unsigned short)(u >> 16);
}
__device__ __forceinline__ float sigm(float x) {
    return __builtin_amdgcn_rcpf(1.f + __expf(-x));
}
__device__ __forceinline__ float tanh_f(float x) {
    float e = __expf(-2.f * fabsf(x));
    float t = (1.f - e) * __builtin_amdgcn_rcpf(1.f + e);
    return copysignf(t, x);
}

// agent-coherent 16B load (sc0 sc1: MALL path). offset: 13-bit signed.
template <int OFF>
__device__ __forceinline__ bf16x8 ldcc(const unsigned short* p) {
    bf16x8 d;
    asm volatile("global_load_dwordx4 %0, %1, off offset:%c2 sc0 sc1"
                 : "=v"(d) : "v"(p), "i"(OFF));
    return d;
}
// 4 A-frags: this wave's K-half = 4 producer tiles at +j*1024 bytes
#define LD4T(d, P)                                      \
    do {                                                \
        d[0] = ldcc<0>(P);    d[1] = ldcc<1024>(P);     \
        d[2] = ldcc<2048>(P); d[3] = ldcc<3072>(P);     \
    } while (0)

__device__ __forceinline__ void vm_drain() {
    asm volatile("s_waitcnt vmcnt(0)" ::: "memory");
    __builtin_amdgcn_sched_barrier(0);  // rule #18
}
__device__ __forceinline__ int fdirty(bf16x8 f) {
    i32x4 d = __builtin_bit_cast(i32x4, f);
    return ((d.x & 0xFFFF) == SENT) | ((d.z & 0xFFFF) == SENT);
}

// ---------------- x [B,T,V] fp32 -> xT [T,B,V] bf16 ----------------
__global__ __launch_bounds__(256) void cvt_kernel(const float* __restrict__ x,
                                                  unsigned short* __restrict__ xT) {
    unsigned g = blockIdx.x * 256u + threadIdx.x;
    unsigned base = g * 8u;
    unsigned r = base >> 8;  // r = t*128 + b
    unsigned v = base & 255u;
    unsigned t = r >> 7, b = r & 127u;
    const float4* src = (const float4*)(x + ((size_t)b * Tt + t) * Vt + v);
    float4 f0 = src[0], f1 = src[1];
    union { unsigned short s[8]; int4 q; } o;
    o.s[0] = f2bf(f0.x); o.s[1] = f2bf(f0.y); o.s[2] = f2bf(f0.z); o.s[3] = f2bf(f0.w);
    o.s[4] = f2bf(f1.x); o.s[5] = f2bf(f1.y); o.s[6] = f2bf(f1.z); o.s[7] = f2bf(f1.w);
    *(int4*)(xT + (size_t)r * Vt + v) = o.q;
}

// ---------------- sentinel pre-fill ----------------
__global__ __launch_bounds__(256) void fill_kernel(unsigned short* __restrict__ h) {
    size_t i = ((size_t)blockIdx.x * 256u + threadIdx.x) * 16u;  // shorts
    i32x4 s = (i32x4){0x7FFF7FFF, 0x7FFF7FFF, 0x7FFF7FFF, 0x7FFF7FFF};
    *(i32x4*)(h + i) = s;
    *(i32x4*)(h + i + 8) = s;
}

// ---------------- persistent dataflow recurrence: 128 WGs ----------------
__global__ __launch_bounds__(256) void rec_kernel(
    const float* __restrict__ Wih1, const float* __restrict__ Whh1,
    const float* __restrict__ bih1, const float* __restrict__ bhh1,
    const float* __restrict__ Wih2, const float* __restrict__ Whh2,
    const float* __restrict__ bih2, const float* __restrict__ bhh2,
    const unsigned short* __restrict__ xT,
    unsigned short* h1s, unsigned short* h2s) {
    const int bid = blockIdx.x;
    const int layer = bid >> 6;
    const int cgrp = (bid >> 3) & 7;  // 32 h-cols [32cgrp, 32cgrp+32)
    const int bgrp = bid & 7;         // 16 batch rows [16bgrp, 16bgrp+16)

    const float* Win = layer ? Wih2 : Wih1;
    const float* Whh = layer ? Whh2 : Whh1;
    const float* bi = layer ? bih2 : bih1;
    const float* bh = layer ? bhh2 : bhh1;

    // flat rows: local gate row r (0..127) = gate(r>>5)*32 + col(r&31);
    // global = 256*(r>>5) + 32*cgrp + (r&31). Pad 264 -> <=2-way b128 reads.
    __shared__ unsigned short sW[2][128][264];  // 132KB
    __shared__ float sP[2][4][16][20];          // ks=1 partials, padded (10KB)
    __shared__ unsigned short sH[16][32];       // assembled h tile (1KB)

    const int tid = threadIdx.x;
    {   // stage both matrices: thread -> (row tid>>1, K-half tid&1)
        int row = tid >> 1, seg = (tid & 1) * 128;
        size_t grow = (size_t)(256 * (row >> 5) + 32 * cgrp + (row & 31)) * Vt + seg;
        for (int m = 0; m < 2; ++m) {
            const float* src = (m ? Whh : Win) + grow;
            unsigned short* dst = &sW[m][row][seg];
            for (int k = 0; k < 128; k += 4) {
                float4 f = *(const float4*)(src + k);
                dst[k + 0] = f2bf(f.x); dst[k + 1] = f2bf(f.y);
                dst[k + 2] = f2bf(f.z); dst[k + 3] = f2bf(f.w);
            }
        }
    }
    __syncthreads();

    const int lane = tid & 63;
    const int wv = tid >> 6;
    const int cs = wv >> 1;   // col-half: h-cols [32cgrp+16cs, +16)
    const int ks = wv & 1;    // K-half: h[t-1] cols [128ks, +128)
    const int q = lane >> 4;
    const int ln = lane & 15;

    // bias only on the cell waves (ks==0); partial waves accumulate raw.
    float biasv[4];
#pragma unroll
    for (int nb = 0; nb < 4; ++nb) {
        int grow = 256 * nb + 32 * cgrp + 16 * cs + ln;
        biasv[nb] = ks ? 0.f : (bi[grow] + bh[grow]);
    }
    float cst[4] = {0.f, 0.f, 0.f, 0.f};  // cell state (cell waves only)

    // consumer A-frag base: tiles {4ks..4ks+3}, row ln, cols q*8
    const size_t hbase = (size_t)bgrp * 4096 + ks * 2048 + ln * 32 + q * 8;
    // xT row-major frag: row 16bgrp+ln, K-slice 128ks
    const int xoff = (16 * bgrp + ln) * 256 + 128 * ks + q * 8;
    unsigned short* ob = layer ? h2s : h1s;
    // producer: wave 1 stores the 1KB tile, lane -> 16B flat
    unsigned short* sptr = ob + (size_t)bgrp * 4096 + cgrp * 512 + lane * 8;

    for (int t = 0; t < Tt; ++t) {
        f32x4 acc[4];
#pragma unroll
        for (int nb = 0; nb < 4; ++nb)
            acc[nb] = (f32x4){biasv[nb], biasv[nb], biasv[nb], biasv[nb]};
        bf16x8 a1[4], a2[4];

        if (layer == 0) {
            // x plain loads (cached) -- off the recurrence chain
            const unsigned short* xp = xT + (size_t)t * TS + xoff;
#pragma unroll
            for (int j = 0; j < 4; ++j) a1[j] = *(const bf16x8*)(xp + j * 32);
            const unsigned short* hp = h1s + (size_t)(t - 1) * TS + hbase;
            if (t > 0) LD4T(a2, hp);
            // x-GEMM (K-half ks): 16 MFMA
#pragma unroll
            for (int kbl = 0; kbl < 4; ++kbl)
#pragma unroll
                for (int nb = 0; nb < 4; ++nb) {
                    bf16x8 b = *(const bf16x8*)
                        &sW[0][nb * 32 + 16 * cs + ln][128 * ks + kbl * 32 + q * 8];
                    acc[nb] = MFMA(a1[kbl], b, acc[nb]);
                }
            if (t > 0) {
                for (;;) {  // sentinel poll: 4 frags only
                    vm_drain();
                    int d = 0;
#pragma unroll
                    for (int j = 0; j < 4; ++j) d |= fdirty(a2[j]);
                    if (!__any(d)) break;
                    __builtin_amdgcn_s_sleep(1);
                    LD4T(a2, hp);
                }
#pragma unroll
                for (int kbl = 0; kbl < 4; ++kbl)
#pragma unroll
                    for (int nb = 0; nb < 4; ++nb) {
                        bf16x8 b = *(const bf16x8*)
                            &sW[1][nb * 32 + 16 * cs + ln][128 * ks + kbl * 32 + q * 8];
                        acc[nb] = MFMA(a2[kbl], b, acc[nb]);
                    }
            }
        } else {
            const unsigned short* hp1 = h1s + (size_t)t * TS + hbase;
            const unsigned short* hp2 = h2s + (size_t)(t - 1) * TS + hbase;
            LD4T(a1, hp1);
            if (t > 0) LD4T(a2, hp2);
            unsigned need = (t > 0) ? 3u : 1u;
            for (;;) {  // combined poll: 8 frags total (was 16)
                vm_drain();
                unsigned nm = 0;
                if (need & 1) {
                    int d = 0;
#pragma unroll
                    for (int j = 0; j < 4; ++j) d |= fdirty(a1[j]);
                    if (__any(d)) nm |= 1u;
                }
                if (need & 2) {
                    int d = 0;
#pragma unroll
                    for (int j = 0; j < 4; ++j) d |= fdirty(a2[j]);
                    if (__any(d)) nm |= 2u;
                }
                if (!nm) break;
                need = nm;
                __builtin_amdgcn_s_sleep(1);
                if (nm & 1) LD4T(a1, hp1);
                if (nm & 2) LD4T(a2, hp2);
            }
#pragma unroll
            for (int kbl = 0; kbl < 4; ++kbl)
#pragma unroll
                for (int nb = 0; nb < 4; ++nb) {
                    bf16x8 b = *(const bf16x8*)
                        &sW[0][nb * 32 + 16 * cs + ln][128 * ks + kbl * 32 + q * 8];
                    acc[nb] = MFMA(a1[kbl], b, acc[nb]);
                }
            if (t > 0) {
#pragma unroll
                for (int kbl = 0; kbl < 4; ++kbl)
#pragma unroll
                    for (int nb = 0; nb < 4; ++nb) {
                        bf16x8 b = *(const bf16x8*)
                            &sW[1][nb * 32 + 16 * cs + ln][128 * ks + kbl * 32 + q * 8];
                        acc[nb] = MFMA(a2[kbl], b, acc[nb]);
                    }
            }
        }

        // ks=1 waves publish their K-half partial (one b128 per n-tile)
        if (ks) {
#pragma unroll
            for (int nb = 0; nb < 4; ++nb)
                *(f32x4*)&sP[cs][nb][ln][q * 4] = acc[nb];
        }
        __syncthreads();  // barrier 1: partials ready
        if (!ks) {
            // reduce + cell; D-col = lane ln = h-col 16cs+ln -> lane-local gates
#pragma unroll
            for (int nb = 0; nb < 4; ++nb)
                acc[nb] += *(const f32x4*)&sP[cs][nb][ln][q * 4];
#pragma unroll
            for (int r = 0; r < 4; ++r) {
                float iv = acc[0][r], fv = acc[1][r];
                float gv = acc[2][r], ov = acc[3][r];
                float cc = sigm(fv) * cst[r] + sigm(iv) * tanh_f(gv);
                cst[r] = cc;
                sH[q * 4 + r][16 * cs + ln] = f2bf(sigm(ov) * tanh_f(cc));
            }
        }
        __syncthreads();  // barrier 2: sH assembled
        if (wv == 1) {    // ONE coalesced 1KB tile store (R9-proven)
            bf16x8 hv = *(const bf16x8*)((const unsigned short*)sH + lane * 8);
            unsigned short* dst = sptr + (size_t)t * TS;
            asm volatile("global_store_dwordx4 %0, %1, off sc0 sc1" ::"v"(dst),
                         "v"(hv) : "memory");
        }
    }
}

// ---------------- out[b,t,:] = h2s_tiled[t] @ w_n^T + fc_b ----------------
__global__ __launch_bounds__(256) void fc_kernel(const unsigned short* __restrict__ h2s,
                                                 const float* __restrict__ fcw,
                                                 const float* __restrict__ fcb,
                                                 float* __restrict__ out) {
    const int bid = blockIdx.x;
    const int rb = bid >> 2;  // t
    const int c0 = (bid & 3) * 64;
    __shared__ unsigned short sWf[64][264];
    __shared__ float sInv[64];
    const int tid = threadIdx.x;
    if (tid < 64) {
        const float* wr = fcw + (size_t)(c0 + tid) * 256;
        float s = 0.f;
        for (int k = 0; k < 256; k += 4) {
            float4 f = *(const float4*)(wr + k);
            s += f.x * f.x + f.y * f.y + f.z * f.z + f.w * f.w;
        }
        sInv[tid] = rsqrtf(s);
    }
    __syncthreads();
    {
        int lr = tid & 63, seg = tid >> 6;
        float inv = sInv[lr];
        const float* wr = fcw + (size_t)(c0 + lr) * 256 + seg * 64;
        unsigned short* dst = &sWf[lr][seg * 64];
        for (int k = 0; k < 64; k += 4) {
            float4 f = *(const float4*)(wr + k);
            dst[k + 0] = f2bf(f.x * inv); dst[k + 1] = f2bf(f.y * inv);
            dst[k + 2] = f2bf(f.z * inv); dst[k + 3] = f2bf(f.w * inv);
        }
    }
    __syncthreads();
    const int lane = tid & 63, w = tid >> 6, q = lane >> 4, ln = lane & 15;
    f32x4 acc[2][4];
    for (int rk = 0; rk < 2; ++rk)
        for (int nb = 0; nb < 4; ++nb) {
            float bv = fcb[c0 + nb * 16 + ln];
            acc[rk][nb] = (f32x4){bv, bv, bv, bv};
        }
    // tiled h2: [bgrp][cgrp][16][32]; wave w covers bgrps {2w, 2w+1}
    const unsigned short* P0 =
        h2s + (size_t)rb * TS + (2 * w) * 4096 + ln * 32 + q * 8;
    const unsigned short* P1 = P0 + 4096;
    for (int kb = 0; kb < 8; ++kb) {
        bf16x8 a0 = *(const bf16x8*)(P0 + kb * 512);
        bf16x8 a1 = *(const bf16x8*)(P1 + kb * 512);
        for (int nb = 0; nb < 4; ++nb) {
            bf16x8 b = *(const bf16x8*)&sWf[nb * 16 + ln][kb * 32 + q * 8];
            acc[0][nb] = MFMA(a0, b, acc[0][nb]);
            acc[1][nb] = MFMA(a1, b, acc[1][nb]);
        }
    }
    for (int rk = 0; rk < 2; ++rk)
        for (int nb = 0; nb < 4; ++nb)
            for (int r = 0; r < 4; ++r) {
                int bb = 32 * w + rk * 16 + q * 4 + r;
                int o = c0 + nb * 16 + ln;
                out[((size_t)bb * Tt + rb) * 256 + o] = acc[rk][nb][r];
            }
}

extern "C" void kernel_launch(void* const* d_in, const int* in_sizes, int n_in,
                              void* d_out, int out_size, void* d_ws, size_t ws_size,
                              hipStream_t stream) {
    const float* x    = (const float*)d_in[0];
    const float* Wih1 = (const float*)d_in[1];
    const float* Whh1 = (const float*)d_in[2];
    const float* bih1 = (const float*)d_in[3];
    const float* bhh1 = (const float*)d_in[4];
    const float* Wih2 = (const float*)d_in[5];
    const float* Whh2 = (const float*)d_in[6];
    const float* bih2 = (const float*)d_in[7];
    const float* bhh2 = (const float*)d_in[8];
    const float* fcw  = (const float*)d_in[9];
    const float* fcb  = (const float*)d_in[10];

    char* ws = (char*)d_ws;
    unsigned short* xT  = (unsigned short*)ws;         // 64MB
    unsigned short* h1s = xT + (size_t)Tt * TS;        // 64MB
    unsigned short* h2s = h1s + (size_t)Tt * TS;       // 64MB

    fill_kernel<<<16384, 256, 0, stream>>>(h1s);  // h1s+h2s contiguous 128MB
    cvt_kernel<<<16384, 256, 0, stream>>>(x, xT);
    rec_kernel<<<128, 256, 0, stream>>>(Wih1, Whh1, bih1, bhh1,
                                        Wih2, Whh2, bih2, bhh2,
                                        xT, h1s, h2s);
    fc_kernel<<<4096, 256, 0, stream>>>(h2s, fcw, fcb, (float*)d_out);
}